// Round 3
// baseline (595.725 us; speedup 1.0000x reference)
//
#include <hip/hip_runtime.h>
#include <stdint.h>

typedef __attribute__((ext_vector_type(8))) __bf16 bf16x8;
typedef __attribute__((ext_vector_type(4))) float f32x4;
typedef __attribute__((ext_vector_type(4))) unsigned int uint4v;
typedef __attribute__((ext_vector_type(2))) unsigned int uint2v;

#define DI __device__ __forceinline__

static constexpr int B_ = 2048;
static constexpr int T_ = 100;

DI float bf2f(unsigned short u){
  unsigned int i = ((unsigned int)u) << 16;
  float f; __builtin_memcpy(&f, &i, 4); return f;
}
DI unsigned short f2bf(float f){
  unsigned int x; __builtin_memcpy(&x, &f, 4);
  unsigned int r = (x + 0x7fffu + ((x >> 16) & 1u)) >> 16;
  return (unsigned short)r;
}
DI float sig_(float x){ return 1.0f / (1.0f + __expf(-x)); }
DI float tanh_(float x){ return 1.0f - 2.0f / (__expf(2.0f * x) + 1.0f); }

// ---------------------------------------------------------------------------
// Pack all weights (fp32 in) into split hi/lo bf16 MFMA B-fragments.
// frag slot 2*fid+0 = hi piece, 2*fid+1 = lo piece. fid layout:
// L1(4096) L2(1536) L3(2048) L4(4096) PROJ(512) = 12288 frags, 24576 slots.
// B-frag: lane l holds B[k = 32*s + 8*(l>>4) + e][col = 16*n + (l&15)], e=0..7.
// ---------------------------------------------------------------------------
__global__ __launch_bounds__(256) void prep_frags(
    const float* __restrict__ e1_wih, const float* __restrict__ e1_whh,
    const float* __restrict__ e2_wih, const float* __restrict__ e2_whh,
    const float* __restrict__ d1_whh,
    const float* __restrict__ d2_wih, const float* __restrict__ d2_whh,
    const float* __restrict__ w_out,
    unsigned short* __restrict__ dst)
{
  int ofid = blockIdx.x * 256 + threadIdx.x;
  if (ofid >= 24576) return;
  int piece = ofid & 1, fid = ofid >> 1;
  int layer, local, KS;
  if (fid < 4096)      { layer = 0; local = fid;         KS = 4; }
  else if (fid < 5632) { layer = 1; local = fid - 4096;  KS = 3; }
  else if (fid < 7680) { layer = 2; local = fid - 5632;  KS = 2; }
  else if (fid < 11776){ layer = 3; local = fid - 7680;  KS = 4; }
  else                 { layer = 4; local = fid - 11776; KS = 2; }
  int lane = local & 63;
  int ns = local >> 6;
  int s = ns % KS, n = ns / KS;
  int col = 16 * n + (lane & 15);
  int kb = 32 * s + 8 * (lane >> 4);
  union { unsigned short u[8]; uint4v v; } pk;
  #pragma unroll
  for (int e = 0; e < 8; ++e){
    int k = kb + e;
    float w = 0.0f;
    if (layer == 0){                       // I=51 pad64 | H=64 ; K=128, C=256
      if (k < 51) w = e1_wih[col * 51 + k];
      else if (k >= 64) w = e1_whh[col * 64 + (k - 64)];
    } else if (layer == 1){                // I=64 | H=24 pad32; K=96, C=128
      int q = col >> 5, jj = col & 31;
      if (jj < 24){
        int r = q * 24 + jj;
        if (k < 64) w = e2_wih[r * 64 + k];
        else if (k < 88) w = e2_whh[r * 24 + (k - 64)];
      }
    } else if (layer == 2){                // recurrent only; K=64, C=256
      w = d1_whh[col * 64 + k];
    } else if (layer == 3){                // I=64 | H=64; K=128, C=256
      if (k < 64) w = d2_wih[col * 64 + k];
      else w = d2_whh[col * 64 + (k - 64)];
    } else {                               // proj: K=64, C=64 (51 used)
      if (col < 51) w = w_out[col * 64 + k];
    }
    unsigned short hi = f2bf(w);
    pk.u[e] = piece ? f2bf(w - bf2f(hi)) : hi;
  }
  *(uint4v*)(dst + (size_t)ofid * 8) = pk.v;
}

// Decoder-1 constant input contribution (exact fp32):
// gx[s][col] = b_ih[col] + b_hh[col] + z[s,:]·W_ih[col,:]
__global__ __launch_bounds__(256) void gx_k(
    const float* __restrict__ z, const float* __restrict__ d1_wih,
    const float* __restrict__ bih, const float* __restrict__ bhh,
    float* __restrict__ gx)
{
  int s = blockIdx.x, col = threadIdx.x;
  float acc = bih[col] + bhh[col];
  #pragma unroll
  for (int k = 0; k < 24; ++k)
    acc += z[s * 24 + k] * d1_wih[col * 24 + k];
  gx[s * 256 + col] = acc;
}

// ---------------------------------------------------------------------------
// Recurrent LSTM layer, split-bf16 (hi/lo) 3-MFMA fp32 emulation.
// Block: 4 waves, BROWS batch rows; each wave owns the 4 gate col-tiles of
// the same 16 j-columns -> i,f,g,o combine in-lane. A (LDS, hi+lo tiles):
// [BROWS][KPAD pad] = [x_t | h_{t-1}]; B-frags (hi+lo) in registers.
// Inter-layer h I/O is fp32 global.
// ---------------------------------------------------------------------------
template<int IDIM, int HDIM, int KPAD, int BROWS, bool HAS_XSEQ, bool CONST_GX, bool WRITE_SEQ>
__global__ __launch_bounds__(256, 1) void lstm_k(
    const float* __restrict__ xseq,
    const float* __restrict__ gxin,
    const unsigned short* __restrict__ bfragu,
    const float* __restrict__ bih,
    const float* __restrict__ bhh,
    float* __restrict__ hout,
    float* __restrict__ zout)
{
  constexpr int KS = KPAD / 32;
  constexpr int SA = KPAD + 8;                  // ushorts per A row (16B-mult stride)
  constexpr int HOFF = HAS_XSEQ ? 64 : 0;       // h section start in A
  constexpr int CPAD = (HDIM == 64) ? 256 : 128;
  constexpr int GT = CPAD / 64;                 // col-tile stride between gates
  constexpr int NX = BROWS / 4;                 // x prefetch regs per thread
  __shared__ __align__(16) unsigned short AldH[BROWS * SA];
  __shared__ __align__(16) unsigned short AldL[BROWS * SA];

  const int tid = threadIdx.x, lane = tid & 63, wid = tid >> 6;
  const int wcol = (HDIM == 64) ? wid : (wid & 1);
  const int rowbase = (HDIM == 64) ? 0 : 16 * (wid >> 1);
  const int l15 = lane & 15, l4 = lane >> 4;
  const int jj = 16 * wcol + l15;               // hidden index (may be >=HDIM pad)
  const int s0 = blockIdx.x * BROWS;

  const bf16x8* bfrag = (const bf16x8*)bfragu;
  bf16x8 bfrH[4][KS], bfrL[4][KS];
  #pragma unroll
  for (int g = 0; g < 4; ++g)
    #pragma unroll
    for (int s = 0; s < KS; ++s){
      size_t idx = (size_t)(((wcol + GT * g) * KS + s) * 64 + lane);
      bfrH[g][s] = bfrag[2 * idx];
      bfrL[g][s] = bfrag[2 * idx + 1];
    }

  f32x4 init[4];
  if constexpr (CONST_GX){
    #pragma unroll
    for (int g = 0; g < 4; ++g){
      #pragma unroll
      for (int r = 0; r < 4; ++r)
        init[g][r] = gxin[(size_t)(s0 + rowbase + 4 * l4 + r) * CPAD + (jj + (CPAD / 4) * g)];
    }
  } else {
    #pragma unroll
    for (int g = 0; g < 4; ++g){
      float b = 0.0f;
      if (jj < HDIM) b = bih[g * HDIM + jj] + bhh[g * HDIM + jj];
      init[g] = (f32x4){b, b, b, b};
    }
  }

  for (int i = tid; i < BROWS * SA; i += 256){ AldH[i] = 0; AldL[i] = 0; }
  __syncthreads();                               // zeros before x0 staging

  if constexpr (HAS_XSEQ){                       // stage x_0 (fp32 -> hi/lo)
    #pragma unroll
    for (int it = 0; it < NX; ++it){
      int idx = tid + it * 256;
      int row = idx >> 6, k = idx & 63;
      float v = 0.0f;
      if (IDIM != 51 || k < 51)
        v = xseq[((size_t)(s0 + row) * T_ + 0) * IDIM + k];
      unsigned short hi = f2bf(v);
      AldH[row * SA + k] = hi;
      AldL[row * SA + k] = f2bf(v - bf2f(hi));
    }
  }

  float cc[4] = {0.f, 0.f, 0.f, 0.f};
  float xr[NX > 0 ? NX : 1];

  #pragma unroll 1
  for (int t = 0; t < T_; ++t){
    __syncthreads();                             // x_t / h_{t-1} visible
    if constexpr (WRITE_SEQ){
      if (t > 0){                                // coalesced copy-out of h_{t-1} (fp32)
        int row = tid >> 4, ch = tid & 15;
        union { uint2v v; unsigned short u[4]; } H, L;
        H.v = *(const uint2v*)&AldH[row * SA + HOFF + ch * 4];
        L.v = *(const uint2v*)&AldL[row * SA + HOFF + ch * 4];
        f32x4 o;
        #pragma unroll
        for (int j = 0; j < 4; ++j) o[j] = bf2f(H.u[j]) + bf2f(L.u[j]);
        *(f32x4*)&hout[((size_t)(s0 + row) * T_ + (t - 1)) * 64 + ch * 4] = o;
      }
    }
    if constexpr (HAS_XSEQ){                     // prefetch x_{t+1} into regs
      if (t + 1 < T_){
        #pragma unroll
        for (int it = 0; it < NX; ++it){
          int idx = tid + it * 256;
          int row = idx >> 6, k = idx & 63;
          xr[it] = (IDIM != 51 || k < 51)
                 ? xseq[((size_t)(s0 + row) * T_ + (t + 1)) * IDIM + k] : 0.0f;
        }
      }
    }
    bf16x8 afH[KS], afL[KS];
    #pragma unroll
    for (int s = 0; s < KS; ++s){
      afH[s] = *(const bf16x8*)&AldH[(rowbase + l15) * SA + 32 * s + 8 * l4];
      afL[s] = *(const bf16x8*)&AldL[(rowbase + l15) * SA + 32 * s + 8 * l4];
    }
    f32x4 acc[4];
    #pragma unroll
    for (int g = 0; g < 4; ++g) acc[g] = init[g];
    #pragma unroll
    for (int s = 0; s < KS; ++s)
      #pragma unroll
      for (int g = 0; g < 4; ++g)
        acc[g] = __builtin_amdgcn_mfma_f32_16x16x32_bf16(afH[s], bfrH[g][s], acc[g], 0, 0, 0);
    #pragma unroll
    for (int s = 0; s < KS; ++s)
      #pragma unroll
      for (int g = 0; g < 4; ++g)
        acc[g] = __builtin_amdgcn_mfma_f32_16x16x32_bf16(afH[s], bfrL[g][s], acc[g], 0, 0, 0);
    #pragma unroll
    for (int s = 0; s < KS; ++s)
      #pragma unroll
      for (int g = 0; g < 4; ++g)
        acc[g] = __builtin_amdgcn_mfma_f32_16x16x32_bf16(afL[s], bfrH[g][s], acc[g], 0, 0, 0);

    unsigned short hbH[4], hbL[4];
    float hv[4];
    #pragma unroll
    for (int r = 0; r < 4; ++r){
      float iv = sig_(acc[0][r]);
      float fv = sig_(acc[1][r]);
      float gv = tanh_(acc[2][r]);
      float ov = sig_(acc[3][r]);
      cc[r] = fv * cc[r] + iv * gv;
      hv[r] = ov * tanh_(cc[r]);
      hbH[r] = f2bf(hv[r]);
      hbL[r] = f2bf(hv[r] - bf2f(hbH[r]));
    }
    if constexpr (!WRITE_SEQ){                   // encoder-2: emit final h as fp32 z
      if (t == T_ - 1 && jj < HDIM){
        #pragma unroll
        for (int r = 0; r < 4; ++r)
          zout[(size_t)(s0 + rowbase + 4 * l4 + r) * HDIM + jj] = hv[r];
      }
    }
    __syncthreads();                             // all A reads done
    #pragma unroll
    for (int r = 0; r < 4; ++r){
      AldH[(rowbase + 4 * l4 + r) * SA + HOFF + jj] = hbH[r];
      AldL[(rowbase + 4 * l4 + r) * SA + HOFF + jj] = hbL[r];
    }
    if constexpr (HAS_XSEQ){                     // write prefetched x_{t+1}
      if (t + 1 < T_){
        #pragma unroll
        for (int it = 0; it < NX; ++it){
          int idx = tid + it * 256;
          int row = idx >> 6, k = idx & 63;
          unsigned short hi = f2bf(xr[it]);
          AldH[row * SA + k] = hi;
          AldL[row * SA + k] = f2bf(xr[it] - bf2f(hi));
        }
      }
    }
  }
  __syncthreads();
  if constexpr (WRITE_SEQ){                      // final h_{T-1}
    int row = tid >> 4, ch = tid & 15;
    union { uint2v v; unsigned short u[4]; } H, L;
    H.v = *(const uint2v*)&AldH[row * SA + HOFF + ch * 4];
    L.v = *(const uint2v*)&AldL[row * SA + HOFF + ch * 4];
    f32x4 o;
    #pragma unroll
    for (int j = 0; j < 4; ++j) o[j] = bf2f(H.u[j]) + bf2f(L.u[j]);
    *(f32x4*)&hout[((size_t)(s0 + row) * T_ + (T_ - 1)) * 64 + ch * 4] = o;
  }
}

// ---------------------------------------------------------------------------
// Final projection: [B*T,64](fp32) @ [64,51] + b -> FP32 out, split-MFMA.
// ---------------------------------------------------------------------------
__global__ __launch_bounds__(256) void proj_k(
    const float* __restrict__ d2out,
    const unsigned short* __restrict__ bfragu,
    const float* __restrict__ b_out,
    float* __restrict__ out)
{
  __shared__ __align__(16) unsigned short AldH[64 * 72];
  __shared__ __align__(16) unsigned short AldL[64 * 72];
  __shared__ __align__(16) float Sst[64 * 51];
  const int tid = threadIdx.x, lane = tid & 63, wid = tid >> 6;
  const int l15 = lane & 15, l4 = lane >> 4;
  const size_t row0 = (size_t)blockIdx.x * 64;

  const bf16x8* bfrag = (const bf16x8*)bfragu;
  bf16x8 bfrH[4][2], bfrL[4][2];
  #pragma unroll
  for (int n = 0; n < 4; ++n)
    #pragma unroll
    for (int s = 0; s < 2; ++s){
      size_t idx = (size_t)((n * 2 + s) * 64 + lane);
      bfrH[n][s] = bfrag[2 * idx];
      bfrL[n][s] = bfrag[2 * idx + 1];
    }
  float bias[4];
  #pragma unroll
  for (int n = 0; n < 4; ++n){
    int col = 16 * n + l15;
    bias[n] = (col < 51) ? b_out[col] : 0.0f;
  }
  #pragma unroll
  for (int it = 0; it < 16; ++it){
    int idx = tid + it * 256;
    int row = idx >> 6, k = idx & 63;
    float v = d2out[(row0 + row) * 64 + k];
    unsigned short hi = f2bf(v);
    AldH[row * 72 + k] = hi;
    AldL[row * 72 + k] = f2bf(v - bf2f(hi));
  }
  __syncthreads();
  bf16x8 afH[2], afL[2];
  #pragma unroll
  for (int s = 0; s < 2; ++s){
    afH[s] = *(const bf16x8*)&AldH[(16 * wid + l15) * 72 + 32 * s + 8 * l4];
    afL[s] = *(const bf16x8*)&AldL[(16 * wid + l15) * 72 + 32 * s + 8 * l4];
  }
  f32x4 acc[4];
  #pragma unroll
  for (int n = 0; n < 4; ++n){
    acc[n] = (f32x4){bias[n], bias[n], bias[n], bias[n]};
    #pragma unroll
    for (int s = 0; s < 2; ++s){
      acc[n] = __builtin_amdgcn_mfma_f32_16x16x32_bf16(afH[s], bfrH[n][s], acc[n], 0, 0, 0);
      acc[n] = __builtin_amdgcn_mfma_f32_16x16x32_bf16(afH[s], bfrL[n][s], acc[n], 0, 0, 0);
      acc[n] = __builtin_amdgcn_mfma_f32_16x16x32_bf16(afL[s], bfrH[n][s], acc[n], 0, 0, 0);
    }
  }
  #pragma unroll
  for (int n = 0; n < 4; ++n){
    int col = 16 * n + l15;
    if (col < 51){
      #pragma unroll
      for (int r = 0; r < 4; ++r)
        Sst[(16 * wid + 4 * l4 + r) * 51 + col] = acc[n][r];
    }
  }
  __syncthreads();
  const uint4v* src = (const uint4v*)Sst;
  uint4v* dst = (uint4v*)(out + row0 * 51);
  for (int i = tid; i < 816; i += 256) dst[i] = src[i];   // 64*51*4B = 13056B
}

extern "C" void kernel_launch(void* const* d_in, const int* in_sizes, int n_in,
                              void* d_out, int out_size, void* d_ws, size_t ws_size,
                              hipStream_t stream)
{
  (void)in_sizes; (void)n_in; (void)out_size; (void)ws_size;
  const float* x      = (const float*)d_in[0];
  const float* e1_wih = (const float*)d_in[1];
  const float* e1_whh = (const float*)d_in[2];
  const float* e1_bih = (const float*)d_in[3];
  const float* e1_bhh = (const float*)d_in[4];
  const float* e2_wih = (const float*)d_in[5];
  const float* e2_whh = (const float*)d_in[6];
  const float* e2_bih = (const float*)d_in[7];
  const float* e2_bhh = (const float*)d_in[8];
  const float* d1_wih = (const float*)d_in[9];
  const float* d1_whh = (const float*)d_in[10];
  const float* d1_bih = (const float*)d_in[11];
  const float* d1_bhh = (const float*)d_in[12];
  const float* d2_wih = (const float*)d_in[13];
  const float* d2_whh = (const float*)d_in[14];
  const float* d2_bih = (const float*)d_in[15];
  const float* d2_bhh = (const float*)d_in[16];
  const float* w_out  = (const float*)d_in[17];
  const float* b_out  = (const float*)d_in[18];

  char* ws = (char*)d_ws;
  unsigned short* bfrag = (unsigned short*)ws;                   // 393,216 B
  // frag byte offsets (fid*32: hi/lo interleaved, 16B per piece)
  const size_t BF_L2 = 131072, BF_L3 = 180224, BF_L4 = 245760, BF_PR = 376832;
  float* buf1  = (float*)(ws + 393216);                          // 52,428,800 B (B*T*64 f32)
  float* zbuf  = (float*)(ws + 393216 + 52428800);               // 196,608 B
  float* gxbuf = (float*)(ws + 393216 + 52428800 + 196608);      // 2,097,152 B

  prep_frags<<<96, 256, 0, stream>>>(e1_wih, e1_whh, e2_wih, e2_whh,
                                     d1_whh, d2_wih, d2_whh, w_out, bfrag);
  // encoder 1: x[B,T,51] -> out1[B,T,64] (buf1)
  lstm_k<51, 64, 128, 16, true, false, true><<<128, 256, 0, stream>>>(
      x, nullptr, bfrag, e1_bih, e1_bhh, buf1, nullptr);
  // encoder 2: buf1 -> z[B,24] (final hidden only)
  lstm_k<64, 24, 96, 32, true, false, false><<<64, 256, 0, stream>>>(
      buf1, nullptr, bfrag + BF_L2 / 2, e2_bih, e2_bhh, nullptr, zbuf);
  // decoder-1 constant input contribution (exact fp32)
  gx_k<<<2048, 256, 0, stream>>>(zbuf, d1_wih, d1_bih, d1_bhh, gxbuf);
  // decoder 1: const gx -> d1out (buf1, overwrites out1 after e2 consumed it)
  lstm_k<64, 64, 64, 16, false, true, true><<<128, 256, 0, stream>>>(
      nullptr, gxbuf, bfrag + BF_L3 / 2, nullptr, nullptr, buf1, nullptr);
  // decoder 2: buf1 -> buf1 in place (h[t-1] written only after x[t+1] prefetched)
  lstm_k<64, 64, 128, 16, true, false, true><<<128, 256, 0, stream>>>(
      buf1, nullptr, bfrag + BF_L4 / 2, d2_bih, d2_bhh, buf1, nullptr);
  // projection -> recon[B,T,51] fp32
  proj_k<<<3200, 256, 0, stream>>>(buf1, bfrag + BF_PR / 2, b_out, (float*)d_out);
}

// Round 4
// 419.921 us; speedup vs baseline: 1.4187x; 1.4187x over previous
//
#include <hip/hip_runtime.h>
#include <stdint.h>

typedef __attribute__((ext_vector_type(8))) __bf16 bf16x8;
typedef __attribute__((ext_vector_type(4))) float f32x4;
typedef __attribute__((ext_vector_type(4))) unsigned int uint4v;
typedef __attribute__((ext_vector_type(2))) unsigned int uint2v;

#define DI __device__ __forceinline__

static constexpr int B_ = 2048;
static constexpr int T_ = 100;

DI float bf2f(unsigned short u){
  unsigned int i = ((unsigned int)u) << 16;
  float f; __builtin_memcpy(&f, &i, 4); return f;
}
DI unsigned short f2bf(float f){
  unsigned int x; __builtin_memcpy(&x, &f, 4);
  unsigned int r = (x + 0x7fffu + ((x >> 16) & 1u)) >> 16;
  return (unsigned short)r;
}
DI float rcp_(float x){ return __builtin_amdgcn_rcpf(x); }
DI float sig_(float x){ return rcp_(1.0f + __expf(-x)); }
DI float tanh_(float x){ return 1.0f - 2.0f * rcp_(__expf(2.0f * x) + 1.0f); }

// ---------------------------------------------------------------------------
// Pack all weights (fp32 in) into split hi/lo bf16 MFMA B-fragments.
// frag slot 2*fid+0 = hi piece, 2*fid+1 = lo piece. fid layout:
// L1(4096) L2(1536) L3(2048) L4(4096) PROJ(512) = 12288 frags, 24576 slots.
// B-frag: lane l holds B[k = 32*s + 8*(l>>4) + e][col = 16*n + (l&15)], e=0..7.
// ---------------------------------------------------------------------------
__global__ __launch_bounds__(256) void prep_frags(
    const float* __restrict__ e1_wih, const float* __restrict__ e1_whh,
    const float* __restrict__ e2_wih, const float* __restrict__ e2_whh,
    const float* __restrict__ d1_whh,
    const float* __restrict__ d2_wih, const float* __restrict__ d2_whh,
    const float* __restrict__ w_out,
    unsigned short* __restrict__ dst)
{
  int ofid = blockIdx.x * 256 + threadIdx.x;
  if (ofid >= 24576) return;
  int piece = ofid & 1, fid = ofid >> 1;
  int layer, local, KS;
  if (fid < 4096)      { layer = 0; local = fid;         KS = 4; }
  else if (fid < 5632) { layer = 1; local = fid - 4096;  KS = 3; }
  else if (fid < 7680) { layer = 2; local = fid - 5632;  KS = 2; }
  else if (fid < 11776){ layer = 3; local = fid - 7680;  KS = 4; }
  else                 { layer = 4; local = fid - 11776; KS = 2; }
  int lane = local & 63;
  int ns = local >> 6;
  int s = ns % KS, n = ns / KS;
  int col = 16 * n + (lane & 15);
  int kb = 32 * s + 8 * (lane >> 4);
  union { unsigned short u[8]; uint4v v; } pk;
  #pragma unroll
  for (int e = 0; e < 8; ++e){
    int k = kb + e;
    float w = 0.0f;
    if (layer == 0){                       // I=51 pad64 | H=64 ; K=128, C=256
      if (k < 51) w = e1_wih[col * 51 + k];
      else if (k >= 64) w = e1_whh[col * 64 + (k - 64)];
    } else if (layer == 1){                // I=64 | H=24 pad32; K=96, C=128
      int q = col >> 5, jj = col & 31;
      if (jj < 24){
        int r = q * 24 + jj;
        if (k < 64) w = e2_wih[r * 64 + k];
        else if (k < 88) w = e2_whh[r * 24 + (k - 64)];
      }
    } else if (layer == 2){                // recurrent only; K=64, C=256
      w = d1_whh[col * 64 + k];
    } else if (layer == 3){                // I=64 | H=64; K=128, C=256
      if (k < 64) w = d2_wih[col * 64 + k];
      else w = d2_whh[col * 64 + (k - 64)];
    } else {                               // proj: K=64, C=64 (51 used)
      if (col < 51) w = w_out[col * 64 + k];
    }
    unsigned short hi = f2bf(w);
    pk.u[e] = piece ? f2bf(w - bf2f(hi)) : hi;
  }
  *(uint4v*)(dst + (size_t)ofid * 8) = pk.v;
}

// Decoder-1 constant input contribution (exact fp32):
// gx[s][col] = b_ih[col] + b_hh[col] + z[s,:]·W_ih[col,:]
__global__ __launch_bounds__(256) void gx_k(
    const float* __restrict__ z, const float* __restrict__ d1_wih,
    const float* __restrict__ bih, const float* __restrict__ bhh,
    float* __restrict__ gx)
{
  int s = blockIdx.x, col = threadIdx.x;
  float acc = bih[col] + bhh[col];
  #pragma unroll
  for (int k = 0; k < 24; ++k)
    acc += z[s * 24 + k] * d1_wih[col * 24 + k];
  gx[s * 256 + col] = acc;
}

// ---------------------------------------------------------------------------
// Recurrent LSTM layer, split-bf16 (hi/lo) 3-MFMA fp32 emulation.
// Double-buffered LDS state; ONE raw barrier per step (lgkmcnt only — no
// vmcnt drain); x prefetched 2 steps deep in registers. Step t reads
// buf[t&1] (x_t | h_{t-1}), writes buf[(t+1)&1].
// ---------------------------------------------------------------------------
template<int IDIM, int HDIM, int KPAD, int BROWS, bool HAS_XSEQ, bool CONST_GX, bool WRITE_SEQ>
__global__ __launch_bounds__(256, 1) void lstm_k(
    const float* xseq,
    const float* __restrict__ gxin,
    const unsigned short* __restrict__ bfragu,
    const float* __restrict__ bih,
    const float* __restrict__ bhh,
    float* hout,
    float* __restrict__ zout)
{
  constexpr int KS = KPAD / 32;
  constexpr int SA = KPAD + 8;                  // ushorts per A row (16B-mult stride)
  constexpr int HOFF = HAS_XSEQ ? 64 : 0;       // h section start in A
  constexpr int CPAD = (HDIM == 64) ? 256 : 128;
  constexpr int GT = CPAD / 64;                 // col-tile stride between gates
  constexpr int NX = HAS_XSEQ ? (BROWS * 64 / 256) : 1;
  __shared__ __align__(16) unsigned short AldH[2][BROWS * SA];
  __shared__ __align__(16) unsigned short AldL[2][BROWS * SA];

  const int tid = threadIdx.x, lane = tid & 63, wid = tid >> 6;
  const int wcol = (HDIM == 64) ? wid : (wid & 1);
  const int rowbase = (HDIM == 64) ? 0 : 16 * (wid >> 1);
  const int l15 = lane & 15, l4 = lane >> 4;
  const int jj = 16 * wcol + l15;               // hidden index (may be >=HDIM pad)
  const int s0 = blockIdx.x * BROWS;

  const bf16x8* bfrag = (const bf16x8*)bfragu;
  bf16x8 bfrH[4][KS], bfrL[4][KS];
  #pragma unroll
  for (int g = 0; g < 4; ++g)
    #pragma unroll
    for (int s = 0; s < KS; ++s){
      size_t idx = (size_t)(((wcol + GT * g) * KS + s) * 64 + lane);
      bfrH[g][s] = bfrag[2 * idx];
      bfrL[g][s] = bfrag[2 * idx + 1];
    }

  f32x4 init[4];
  if constexpr (CONST_GX){
    #pragma unroll
    for (int g = 0; g < 4; ++g){
      #pragma unroll
      for (int r = 0; r < 4; ++r)
        init[g][r] = gxin[(size_t)(s0 + rowbase + 4 * l4 + r) * CPAD + (jj + (CPAD / 4) * g)];
    }
  } else {
    #pragma unroll
    for (int g = 0; g < 4; ++g){
      float b = 0.0f;
      if (jj < HDIM) b = bih[g * HDIM + jj] + bhh[g * HDIM + jj];
      init[g] = (f32x4){b, b, b, b};
    }
  }

  for (int i = tid; i < BROWS * SA; i += 256){
    AldH[0][i] = 0; AldH[1][i] = 0; AldL[0][i] = 0; AldL[1][i] = 0;
  }
  __syncthreads();                               // zeros visible before x0 staging

  if constexpr (HAS_XSEQ){                       // stage x_0 -> buf 0 (fp32 -> hi/lo)
    #pragma unroll
    for (int it = 0; it < NX; ++it){
      int idx = tid + it * 256;
      int row = idx >> 6, k = idx & 63;
      float v = (k < IDIM) ? xseq[((size_t)(s0 + row) * T_ + 0) * IDIM + k] : 0.0f;
      unsigned short hi = f2bf(v);
      AldH[0][row * SA + k] = hi;
      AldL[0][row * SA + k] = f2bf(v - bf2f(hi));
    }
  }
  __syncthreads();

  float cc[4] = {0.f, 0.f, 0.f, 0.f};
  float xsA[NX], xsB[NX];
  if constexpr (HAS_XSEQ){                       // prefetch x_1, x_2
    #pragma unroll
    for (int it = 0; it < NX; ++it){
      int idx = tid + it * 256;
      int row = idx >> 6, k = idx & 63;
      xsA[it] = (k < IDIM) ? xseq[((size_t)(s0 + row) * T_ + 1) * IDIM + k] : 0.0f;
      xsB[it] = (k < IDIM) ? xseq[((size_t)(s0 + row) * T_ + 2) * IDIM + k] : 0.0f;
    }
  }

#define LSTM_STEP(TCUR, BSEL, XW)                                              \
  {                                                                            \
    const int t = (TCUR);                                                      \
    bf16x8 afH[KS], afL[KS];                                                   \
    _Pragma("unroll")                                                          \
    for (int s = 0; s < KS; ++s){                                              \
      afH[s] = *(const bf16x8*)&AldH[BSEL][(rowbase + l15) * SA + 32 * s + 8 * l4]; \
      afL[s] = *(const bf16x8*)&AldL[BSEL][(rowbase + l15) * SA + 32 * s + 8 * l4]; \
    }                                                                          \
    f32x4 acc[4];                                                              \
    _Pragma("unroll") for (int g = 0; g < 4; ++g) acc[g] = init[g];            \
    _Pragma("unroll") for (int s = 0; s < KS; ++s)                             \
      _Pragma("unroll") for (int g = 0; g < 4; ++g)                            \
        acc[g] = __builtin_amdgcn_mfma_f32_16x16x32_bf16(afH[s], bfrH[g][s], acc[g], 0, 0, 0); \
    _Pragma("unroll") for (int s = 0; s < KS; ++s)                             \
      _Pragma("unroll") for (int g = 0; g < 4; ++g)                            \
        acc[g] = __builtin_amdgcn_mfma_f32_16x16x32_bf16(afH[s], bfrL[g][s], acc[g], 0, 0, 0); \
    _Pragma("unroll") for (int s = 0; s < KS; ++s)                             \
      _Pragma("unroll") for (int g = 0; g < 4; ++g)                            \
        acc[g] = __builtin_amdgcn_mfma_f32_16x16x32_bf16(afL[s], bfrH[g][s], acc[g], 0, 0, 0); \
    if constexpr (WRITE_SEQ){                                                  \
      if (t > 0){                                                              \
        int row = tid >> 4, ch = tid & 15;                                     \
        union { uint2v v; unsigned short u[4]; } Hh, Ll;                       \
        Hh.v = *(const uint2v*)&AldH[BSEL][row * SA + HOFF + ch * 4];          \
        Ll.v = *(const uint2v*)&AldL[BSEL][row * SA + HOFF + ch * 4];          \
        f32x4 o;                                                               \
        _Pragma("unroll")                                                      \
        for (int j2 = 0; j2 < 4; ++j2) o[j2] = bf2f(Hh.u[j2]) + bf2f(Ll.u[j2]); \
        *(f32x4*)&hout[((size_t)(s0 + row) * T_ + (t - 1)) * 64 + ch * 4] = o; \
      }                                                                        \
    }                                                                          \
    unsigned short hbH[4], hbL[4];                                             \
    float hv[4];                                                               \
    _Pragma("unroll")                                                          \
    for (int r = 0; r < 4; ++r){                                               \
      float iv = sig_(acc[0][r]);                                              \
      float fv = sig_(acc[1][r]);                                              \
      float gv = tanh_(acc[2][r]);                                             \
      float ov = sig_(acc[3][r]);                                              \
      cc[r] = fv * cc[r] + iv * gv;                                            \
      hv[r] = ov * tanh_(cc[r]);                                               \
      hbH[r] = f2bf(hv[r]);                                                    \
      hbL[r] = f2bf(hv[r] - bf2f(hbH[r]));                                     \
    }                                                                          \
    if constexpr (!WRITE_SEQ){                                                 \
      if (t == T_ - 1 && jj < HDIM){                                           \
        _Pragma("unroll")                                                      \
        for (int r = 0; r < 4; ++r)                                            \
          zout[(size_t)(s0 + rowbase + 4 * l4 + r) * HDIM + jj] = hv[r];       \
      }                                                                        \
    }                                                                          \
    _Pragma("unroll")                                                          \
    for (int r = 0; r < 4; ++r){                                               \
      AldH[BSEL ^ 1][(rowbase + 4 * l4 + r) * SA + HOFF + jj] = hbH[r];        \
      AldL[BSEL ^ 1][(rowbase + 4 * l4 + r) * SA + HOFF + jj] = hbL[r];        \
    }                                                                          \
    if constexpr (HAS_XSEQ){                                                   \
      if (t + 1 < T_){                                                         \
        _Pragma("unroll")                                                      \
        for (int it = 0; it < NX; ++it){                                       \
          int idx = tid + it * 256;                                            \
          int row = idx >> 6, k = idx & 63;                                    \
          unsigned short hi = f2bf(XW[it]);                                    \
          AldH[BSEL ^ 1][row * SA + k] = hi;                                   \
          AldL[BSEL ^ 1][row * SA + k] = f2bf(XW[it] - bf2f(hi));              \
        }                                                                      \
        if (t + 3 < T_){                                                       \
          _Pragma("unroll")                                                    \
          for (int it = 0; it < NX; ++it){                                     \
            int idx = tid + it * 256;                                          \
            int row = idx >> 6, k = idx & 63;                                  \
            XW[it] = (k < IDIM) ? xseq[((size_t)(s0 + row) * T_ + (t + 3)) * IDIM + k] : 0.0f; \
          }                                                                    \
        }                                                                      \
      }                                                                        \
    }                                                                          \
    asm volatile("s_waitcnt lgkmcnt(0)\n\ts_barrier" ::: "memory");            \
  }

  #pragma unroll 1
  for (int tt = 0; tt < T_; tt += 2){
    LSTM_STEP(tt,     0, xsA)
    LSTM_STEP(tt + 1, 1, xsB)
  }
#undef LSTM_STEP

  if constexpr (WRITE_SEQ){                      // final h_{T-1} is in buf[T&1]=buf0
    int row = tid >> 4, ch = tid & 15;
    union { uint2v v; unsigned short u[4]; } Hh, Ll;
    Hh.v = *(const uint2v*)&AldH[0][row * SA + HOFF + ch * 4];
    Ll.v = *(const uint2v*)&AldL[0][row * SA + HOFF + ch * 4];
    f32x4 o;
    #pragma unroll
    for (int j2 = 0; j2 < 4; ++j2) o[j2] = bf2f(Hh.u[j2]) + bf2f(Ll.u[j2]);
    *(f32x4*)&hout[((size_t)(s0 + row) * T_ + (T_ - 1)) * 64 + ch * 4] = o;
  }
}

// ---------------------------------------------------------------------------
// Final projection: [B*T,64](fp32) @ [64,51] + b -> FP32 out, split-MFMA.
// ---------------------------------------------------------------------------
__global__ __launch_bounds__(256) void proj_k(
    const float* __restrict__ d2out,
    const unsigned short* __restrict__ bfragu,
    const float* __restrict__ b_out,
    float* __restrict__ out)
{
  __shared__ __align__(16) unsigned short AldH[64 * 72];
  __shared__ __align__(16) unsigned short AldL[64 * 72];
  __shared__ __align__(16) float Sst[64 * 51];
  const int tid = threadIdx.x, lane = tid & 63, wid = tid >> 6;
  const int l15 = lane & 15, l4 = lane >> 4;
  const size_t row0 = (size_t)blockIdx.x * 64;

  const bf16x8* bfrag = (const bf16x8*)bfragu;
  bf16x8 bfrH[4][2], bfrL[4][2];
  #pragma unroll
  for (int n = 0; n < 4; ++n)
    #pragma unroll
    for (int s = 0; s < 2; ++s){
      size_t idx = (size_t)((n * 2 + s) * 64 + lane);
      bfrH[n][s] = bfrag[2 * idx];
      bfrL[n][s] = bfrag[2 * idx + 1];
    }
  float bias[4];
  #pragma unroll
  for (int n = 0; n < 4; ++n){
    int col = 16 * n + l15;
    bias[n] = (col < 51) ? b_out[col] : 0.0f;
  }
  #pragma unroll
  for (int it = 0; it < 16; ++it){
    int idx = tid + it * 256;
    int row = idx >> 6, k = idx & 63;
    float v = d2out[(row0 + row) * 64 + k];
    unsigned short hi = f2bf(v);
    AldH[row * 72 + k] = hi;
    AldL[row * 72 + k] = f2bf(v - bf2f(hi));
  }
  __syncthreads();
  bf16x8 afH[2], afL[2];
  #pragma unroll
  for (int s = 0; s < 2; ++s){
    afH[s] = *(const bf16x8*)&AldH[(16 * wid + l15) * 72 + 32 * s + 8 * l4];
    afL[s] = *(const bf16x8*)&AldL[(16 * wid + l15) * 72 + 32 * s + 8 * l4];
  }
  f32x4 acc[4];
  #pragma unroll
  for (int n = 0; n < 4; ++n){
    acc[n] = (f32x4){bias[n], bias[n], bias[n], bias[n]};
    #pragma unroll
    for (int s = 0; s < 2; ++s){
      acc[n] = __builtin_amdgcn_mfma_f32_16x16x32_bf16(afH[s], bfrH[n][s], acc[n], 0, 0, 0);
      acc[n] = __builtin_amdgcn_mfma_f32_16x16x32_bf16(afH[s], bfrL[n][s], acc[n], 0, 0, 0);
      acc[n] = __builtin_amdgcn_mfma_f32_16x16x32_bf16(afL[s], bfrH[n][s], acc[n], 0, 0, 0);
    }
  }
  #pragma unroll
  for (int n = 0; n < 4; ++n){
    int col = 16 * n + l15;
    if (col < 51){
      #pragma unroll
      for (int r = 0; r < 4; ++r)
        Sst[(16 * wid + 4 * l4 + r) * 51 + col] = acc[n][r];
    }
  }
  __syncthreads();
  const uint4v* src = (const uint4v*)Sst;
  uint4v* dst = (uint4v*)(out + row0 * 51);
  for (int i = tid; i < 816; i += 256) dst[i] = src[i];   // 64*51*4B = 13056B
}

extern "C" void kernel_launch(void* const* d_in, const int* in_sizes, int n_in,
                              void* d_out, int out_size, void* d_ws, size_t ws_size,
                              hipStream_t stream)
{
  (void)in_sizes; (void)n_in; (void)out_size; (void)ws_size;
  const float* x      = (const float*)d_in[0];
  const float* e1_wih = (const float*)d_in[1];
  const float* e1_whh = (const float*)d_in[2];
  const float* e1_bih = (const float*)d_in[3];
  const float* e1_bhh = (const float*)d_in[4];
  const float* e2_wih = (const float*)d_in[5];
  const float* e2_whh = (const float*)d_in[6];
  const float* e2_bih = (const float*)d_in[7];
  const float* e2_bhh = (const float*)d_in[8];
  const float* d1_wih = (const float*)d_in[9];
  const float* d1_whh = (const float*)d_in[10];
  const float* d1_bih = (const float*)d_in[11];
  const float* d1_bhh = (const float*)d_in[12];
  const float* d2_wih = (const float*)d_in[13];
  const float* d2_whh = (const float*)d_in[14];
  const float* d2_bih = (const float*)d_in[15];
  const float* d2_bhh = (const float*)d_in[16];
  const float* w_out  = (const float*)d_in[17];
  const float* b_out  = (const float*)d_in[18];

  char* ws = (char*)d_ws;
  unsigned short* bfrag = (unsigned short*)ws;                   // 393,216 B
  // frag byte offsets (fid*32: hi/lo interleaved, 16B per piece)
  const size_t BF_L2 = 131072, BF_L3 = 180224, BF_L4 = 245760, BF_PR = 376832;
  float* buf1  = (float*)(ws + 393216);                          // 52,428,800 B (B*T*64 f32)
  float* zbuf  = (float*)(ws + 393216 + 52428800);               // 196,608 B
  float* gxbuf = (float*)(ws + 393216 + 52428800 + 196608);      // 2,097,152 B

  prep_frags<<<96, 256, 0, stream>>>(e1_wih, e1_whh, e2_wih, e2_whh,
                                     d1_whh, d2_wih, d2_whh, w_out, bfrag);
  // encoder 1: x[B,T,51] -> out1[B,T,64] (buf1)
  lstm_k<51, 64, 128, 16, true, false, true><<<128, 256, 0, stream>>>(
      x, nullptr, bfrag, e1_bih, e1_bhh, buf1, nullptr);
  // encoder 2: buf1 -> z[B,24] (final hidden only)
  lstm_k<64, 24, 96, 32, true, false, false><<<64, 256, 0, stream>>>(
      buf1, nullptr, bfrag + BF_L2 / 2, e2_bih, e2_bhh, nullptr, zbuf);
  // decoder-1 constant input contribution (exact fp32)
  gx_k<<<2048, 256, 0, stream>>>(zbuf, d1_wih, d1_bih, d1_bhh, gxbuf);
  // decoder 1: const gx -> d1out (buf1, overwrites out1 after e2 consumed it)
  lstm_k<64, 64, 64, 16, false, true, true><<<128, 256, 0, stream>>>(
      nullptr, gxbuf, bfrag + BF_L3 / 2, nullptr, nullptr, buf1, nullptr);
  // decoder 2: buf1 -> buf1 in place (reads lead writes by >=3 steps)
  lstm_k<64, 64, 128, 16, true, false, true><<<128, 256, 0, stream>>>(
      buf1, nullptr, bfrag + BF_L4 / 2, d2_bih, d2_bhh, buf1, nullptr);
  // projection -> recon[B,T,51] fp32
  proj_k<<<3200, 256, 0, stream>>>(buf1, bfrag + BF_PR / 2, b_out, (float*)d_out);
}

// Round 5
// 404.779 us; speedup vs baseline: 1.4717x; 1.0374x over previous
//
#include <hip/hip_runtime.h>
#include <stdint.h>

typedef __attribute__((ext_vector_type(8))) __bf16 bf16x8;
typedef __attribute__((ext_vector_type(4))) float f32x4;
typedef __attribute__((ext_vector_type(4))) unsigned int uint4v;

#define DI __device__ __forceinline__
#define MFMA_(a,b,c) __builtin_amdgcn_mfma_f32_16x16x32_bf16(a,b,c,0,0,0)

static constexpr int B_ = 2048;
static constexpr int T_ = 100;

DI float bf2f(unsigned short u){
  unsigned int i = ((unsigned int)u) << 16;
  float f; __builtin_memcpy(&f, &i, 4); return f;
}
DI unsigned short f2bf(float f){
  unsigned int x; __builtin_memcpy(&x, &f, 4);
  unsigned int r = (x + 0x7fffu + ((x >> 16) & 1u)) >> 16;
  return (unsigned short)r;
}
DI float rcp_(float x){ return __builtin_amdgcn_rcpf(x); }
DI float sig_(float x){ return rcp_(1.0f + __expf(-x)); }
DI float tanh_(float x){ return 1.0f - 2.0f * rcp_(__expf(2.0f * x) + 1.0f); }

// 3-pass split-bf16 MFMA dot: (Ahi*Bhi) + (Ahi*Blo) + (Alo*Bhi), 3 short chains.
template<int KS>
DI f32x4 dot3(const bf16x8* aH, const bf16x8* aL,
              const bf16x8* bH, const bf16x8* bL, f32x4 ini)
{
  f32x4 p = ini;
  f32x4 q = (f32x4){0.f,0.f,0.f,0.f};
  f32x4 r = (f32x4){0.f,0.f,0.f,0.f};
  #pragma unroll
  for (int s = 0; s < KS; ++s){
    p = MFMA_(aH[s], bH[s], p);
    q = MFMA_(aH[s], bL[s], q);
    r = MFMA_(aL[s], bH[s], r);
  }
  return (p + q) + r;
}

// LSTM pointwise: gates i,f,g,o -> c,h + split-bf16 h.
DI void pw(const f32x4 (&acc)[4], float (&cc)[4], float (&hv)[4],
           unsigned short (&hH)[4], unsigned short (&hL)[4])
{
  #pragma unroll
  for (int r = 0; r < 4; ++r){
    float iv = sig_(acc[0][r]);
    float fv = sig_(acc[1][r]);
    float gv = tanh_(acc[2][r]);
    float ov = sig_(acc[3][r]);
    cc[r] = fv * cc[r] + iv * gv;
    hv[r] = ov * tanh_(cc[r]);
    hH[r] = f2bf(hv[r]);
    hL[r] = f2bf(hv[r] - bf2f(hH[r]));
  }
}

// ---------------------------------------------------------------------------
// Pack all weights (fp32 in) into split hi/lo bf16 MFMA B-fragments.
// slot 2*fid+0 = hi, 2*fid+1 = lo. fid layout:
// L1(4096) L2(1536) L3(2048) L4(4096) PROJ(512) = 12288 frags.
// B-frag: lane l holds B[k = 32*s + 8*(l>>4) + e][col = 16*n + (l&15)], e=0..7.
// ---------------------------------------------------------------------------
__global__ __launch_bounds__(256) void prep_frags(
    const float* __restrict__ e1_wih, const float* __restrict__ e1_whh,
    const float* __restrict__ e2_wih, const float* __restrict__ e2_whh,
    const float* __restrict__ d1_whh,
    const float* __restrict__ d2_wih, const float* __restrict__ d2_whh,
    const float* __restrict__ w_out,
    unsigned short* __restrict__ dst)
{
  int ofid = blockIdx.x * 256 + threadIdx.x;
  if (ofid >= 24576) return;
  int piece = ofid & 1, fid = ofid >> 1;
  int layer, local, KS;
  if (fid < 4096)      { layer = 0; local = fid;         KS = 4; }
  else if (fid < 5632) { layer = 1; local = fid - 4096;  KS = 3; }
  else if (fid < 7680) { layer = 2; local = fid - 5632;  KS = 2; }
  else if (fid < 11776){ layer = 3; local = fid - 7680;  KS = 4; }
  else                 { layer = 4; local = fid - 11776; KS = 2; }
  int lane = local & 63;
  int ns = local >> 6;
  int s = ns % KS, n = ns / KS;
  int col = 16 * n + (lane & 15);
  int kb = 32 * s + 8 * (lane >> 4);
  union { unsigned short u[8]; uint4v v; } pk;
  #pragma unroll
  for (int e = 0; e < 8; ++e){
    int k = kb + e;
    float w = 0.0f;
    if (layer == 0){                       // e1: x(51 pad64)|h1(64); K=128, C=256
      if (k < 51) w = e1_wih[col * 51 + k];
      else if (k >= 64) w = e1_whh[col * 64 + (k - 64)];
    } else if (layer == 1){                // e2: h1(64)|h2(24 pad32); K=96, C=128
      int q = col >> 5, jj = col & 31;
      if (jj < 24){
        int r = q * 24 + jj;
        if (k < 64) w = e2_wih[r * 64 + k];
        else if (k < 88) w = e2_whh[r * 24 + (k - 64)];
      }
    } else if (layer == 2){                // d1 recurrent only; K=64, C=256
      w = d1_whh[col * 64 + k];
    } else if (layer == 3){                // d2: h3(64)|h4(64); K=128, C=256
      if (k < 64) w = d2_wih[col * 64 + k];
      else w = d2_whh[col * 64 + (k - 64)];
    } else {                               // proj: K=64, C=64 (51 used)
      if (col < 51) w = w_out[col * 64 + k];
    }
    unsigned short hi = f2bf(w);
    pk.u[e] = piece ? f2bf(w - bf2f(hi)) : hi;
  }
  *(uint4v*)(dst + (size_t)ofid * 8) = pk.v;
}

// Decoder-1 constant input contribution (exact fp32):
// gx[s][col] = b_ih[col] + b_hh[col] + z[s,:]·W_ih[col,:]
__global__ __launch_bounds__(256) void gx_k(
    const float* __restrict__ z, const float* __restrict__ d1_wih,
    const float* __restrict__ bih, const float* __restrict__ bhh,
    float* __restrict__ gx)
{
  int s = blockIdx.x, col = threadIdx.x;
  float acc = bih[col] + bhh[col];
  #pragma unroll
  for (int k = 0; k < 24; ++k)
    acc += z[s * 24 + k] * d1_wih[col * 24 + k];
  gx[s * 256 + col] = acc;
}

// ---------------------------------------------------------------------------
// F1: fused encoder (e1 + e2), 16 batch rows/block, 4 waves.
// All waves compute e1 (their 16-col gate tile); waves 0,1 additionally run
// e2 with lag 1 (step t computes h2_{t-1}). h1 passes e1->e2 via LDS only.
// No per-step global traffic except x prefetch loads. z written at t=100.
// ---------------------------------------------------------------------------
__global__ __launch_bounds__(256, 1) void fused_enc(
    const float* xseq,
    const unsigned short* __restrict__ bf1u,
    const unsigned short* __restrict__ bf2u,
    const float* __restrict__ e1_bih, const float* __restrict__ e1_bhh,
    const float* __restrict__ e2_bih, const float* __restrict__ e2_bhh,
    float* __restrict__ zout)
{
  constexpr int SA1 = 136;                 // A1 row stride (ushorts): x(64)|h1(64) pad
  constexpr int SA2 = 104;                 // A2 row stride: h1(64)|h2(32) pad
  __shared__ __align__(16) unsigned short A1H[2][16 * SA1], A1L[2][16 * SA1];
  __shared__ __align__(16) unsigned short A2H[2][16 * SA2], A2L[2][16 * SA2];

  const int tid = threadIdx.x, lane = tid & 63, wid = tid >> 6;
  const int l15 = lane & 15, l4 = lane >> 4;
  const int jj = 16 * wid + l15;
  const int s0 = blockIdx.x * 16;
  const bool isE2 = (wid < 2);

  const bf16x8* f1 = (const bf16x8*)bf1u;
  const bf16x8* f2 = (const bf16x8*)bf2u;
  bf16x8 b1H[16], b1L[16];                 // e1 frags [g*4+s]
  #pragma unroll
  for (int g = 0; g < 4; ++g)
    #pragma unroll
    for (int s = 0; s < 4; ++s){
      size_t idx = (size_t)(((wid + 4 * g) * 4 + s) * 64 + lane);
      b1H[g * 4 + s] = f1[2 * idx];
      b1L[g * 4 + s] = f1[2 * idx + 1];
    }
  bf16x8 b2H[12], b2L[12];                 // e2 frags [g*3+s] (waves 0,1)
  if (isE2){
    #pragma unroll
    for (int g = 0; g < 4; ++g)
      #pragma unroll
      for (int s = 0; s < 3; ++s){
        size_t idx = (size_t)(((wid + 2 * g) * 3 + s) * 64 + lane);
        b2H[g * 3 + s] = f2[2 * idx];
        b2L[g * 3 + s] = f2[2 * idx + 1];
      }
  }

  f32x4 init1[4], init2[4];
  #pragma unroll
  for (int g = 0; g < 4; ++g){
    float b = e1_bih[g * 64 + jj] + e1_bhh[g * 64 + jj];
    init1[g] = (f32x4){b, b, b, b};
    float b2 = 0.0f;
    if (isE2 && jj < 24) b2 = e2_bih[g * 24 + jj] + e2_bhh[g * 24 + jj];
    init2[g] = (f32x4){b2, b2, b2, b2};
  }

  for (int i = tid; i < 16 * SA1; i += 256){
    A1H[0][i] = 0; A1H[1][i] = 0; A1L[0][i] = 0; A1L[1][i] = 0;
  }
  for (int i = tid; i < 16 * SA2; i += 256){
    A2H[0][i] = 0; A2H[1][i] = 0; A2L[0][i] = 0; A2L[1][i] = 0;
  }
  __syncthreads();
  #pragma unroll
  for (int it = 0; it < 4; ++it){           // stage x_0
    int idx = tid + it * 256, row = idx >> 6, k = idx & 63;
    float v = (k < 51) ? xseq[((size_t)(s0 + row) * T_ + 0) * 51 + k] : 0.0f;
    unsigned short xh = f2bf(v);
    A1H[0][row * SA1 + k] = xh;
    A1L[0][row * SA1 + k] = f2bf(v - bf2f(xh));
  }
  __syncthreads();

  float xsA[4], xsB[4];
  #pragma unroll
  for (int it = 0; it < 4; ++it){           // prefetch x_1, x_2
    int idx = tid + it * 256, row = idx >> 6, k = idx & 63;
    xsA[it] = (k < 51) ? xseq[((size_t)(s0 + row) * T_ + 1) * 51 + k] : 0.0f;
    xsB[it] = (k < 51) ? xseq[((size_t)(s0 + row) * T_ + 2) * 51 + k] : 0.0f;
  }
  float cc1[4] = {0.f,0.f,0.f,0.f}, cc2[4] = {0.f,0.f,0.f,0.f};

#define ENC_STEP(TCUR, BSEL, XW)                                               \
  {                                                                            \
    const int t = (TCUR);                                                      \
    if (t < T_){  /* e1 step t: all waves */                                   \
      bf16x8 a1H[4], a1L[4];                                                   \
      _Pragma("unroll")                                                        \
      for (int s = 0; s < 4; ++s){                                             \
        a1H[s] = *(const bf16x8*)&A1H[BSEL][l15 * SA1 + 32 * s + 8 * l4];      \
        a1L[s] = *(const bf16x8*)&A1L[BSEL][l15 * SA1 + 32 * s + 8 * l4];      \
      }                                                                        \
      f32x4 acc[4];                                                            \
      _Pragma("unroll")                                                        \
      for (int g = 0; g < 4; ++g)                                              \
        acc[g] = dot3<4>(a1H, a1L, &b1H[g * 4], &b1L[g * 4], init1[g]);        \
      float hv[4]; unsigned short hH[4], hL[4];                                \
      pw(acc, cc1, hv, hH, hL);                                                \
      _Pragma("unroll")                                                        \
      for (int r = 0; r < 4; ++r){                                             \
        int rw = 4 * l4 + r;                                                   \
        A1H[BSEL ^ 1][rw * SA1 + 64 + jj] = hH[r];                             \
        A1L[BSEL ^ 1][rw * SA1 + 64 + jj] = hL[r];                             \
        A2H[BSEL ^ 1][rw * SA2 + jj] = hH[r];                                  \
        A2L[BSEL ^ 1][rw * SA2 + jj] = hL[r];                                  \
      }                                                                        \
      if (t + 1 < T_){                                                         \
        _Pragma("unroll")                                                      \
        for (int it = 0; it < 4; ++it){                                        \
          int idx = tid + it * 256, row = idx >> 6, k = idx & 63;              \
          unsigned short xh = f2bf(XW[it]);                                    \
          A1H[BSEL ^ 1][row * SA1 + k] = xh;                                   \
          A1L[BSEL ^ 1][row * SA1 + k] = f2bf(XW[it] - bf2f(xh));              \
        }                                                                      \
        if (t + 3 < T_){                                                       \
          _Pragma("unroll")                                                    \
          for (int it = 0; it < 4; ++it){                                      \
            int idx = tid + it * 256, row = idx >> 6, k = idx & 63;            \
            XW[it] = (k < 51) ? xseq[((size_t)(s0 + row) * T_ + (t + 3)) * 51 + k] : 0.0f; \
          }                                                                    \
        }                                                                      \
      }                                                                        \
    }                                                                          \
    if (isE2 && t >= 1 && t <= T_){  /* e2 computes h2_{t-1}: waves 0,1 */     \
      bf16x8 a2H[3], a2L[3];                                                   \
      _Pragma("unroll")                                                        \
      for (int s = 0; s < 3; ++s){                                             \
        a2H[s] = *(const bf16x8*)&A2H[BSEL][l15 * SA2 + 32 * s + 8 * l4];      \
        a2L[s] = *(const bf16x8*)&A2L[BSEL][l15 * SA2 + 32 * s + 8 * l4];      \
      }                                                                        \
      f32x4 acc[4];                                                            \
      _Pragma("unroll")                                                        \
      for (int g = 0; g < 4; ++g)                                              \
        acc[g] = dot3<3>(a2H, a2L, &b2H[g * 3], &b2L[g * 3], init2[g]);        \
      float hv[4]; unsigned short hH[4], hL[4];                                \
      pw(acc, cc2, hv, hH, hL);                                                \
      if (jj < 24){                                                            \
        _Pragma("unroll")                                                      \
        for (int r = 0; r < 4; ++r){                                           \
          int rw = 4 * l4 + r;                                                 \
          A2H[BSEL ^ 1][rw * SA2 + 64 + jj] = hH[r];                           \
          A2L[BSEL ^ 1][rw * SA2 + 64 + jj] = hL[r];                           \
        }                                                                      \
        if (t == T_){                                                          \
          _Pragma("unroll")                                                    \
          for (int r = 0; r < 4; ++r)                                          \
            zout[(size_t)(s0 + 4 * l4 + r) * 24 + jj] = hv[r];                 \
        }                                                                      \
      }                                                                        \
    }                                                                          \
    asm volatile("s_waitcnt lgkmcnt(0)\n\ts_barrier" ::: "memory");            \
  }

  #pragma unroll 1
  for (int tt = 0; tt < 102; tt += 2){
    ENC_STEP(tt,     0, xsA)
    ENC_STEP(tt + 1, 1, xsB)
  }
#undef ENC_STEP
}

// ---------------------------------------------------------------------------
// F2: fused decoder (d1 + d2 + proj), 16 rows/block, 4 waves, all roles on
// every wave. Step t: d1 h3_t (t<=99); d2 h4_{t-1} (1<=t<=100); proj of
// h4_{t-2} (t>=2). h3/h4 pass through LDS; only proj output hits HBM.
// ---------------------------------------------------------------------------
__global__ __launch_bounds__(256, 1) void fused_dec(
    const float* __restrict__ gxin,
    const unsigned short* __restrict__ bf3u,
    const unsigned short* __restrict__ bf4u,
    const unsigned short* __restrict__ bfpu,
    const float* __restrict__ d2_bih, const float* __restrict__ d2_bhh,
    const float* __restrict__ b_out,
    float* out)
{
  constexpr int SA3 = 72;                  // A3: h3(64) pad
  constexpr int SA4 = 136;                 // A4: h3(64)|h4(64) pad
  __shared__ __align__(16) unsigned short A3H[2][16 * SA3], A3L[2][16 * SA3];
  __shared__ __align__(16) unsigned short A4H[2][16 * SA4], A4L[2][16 * SA4];

  const int tid = threadIdx.x, lane = tid & 63, wid = tid >> 6;
  const int l15 = lane & 15, l4 = lane >> 4;
  const int jj = 16 * wid + l15;
  const int s0 = blockIdx.x * 16;

  const bf16x8* f3 = (const bf16x8*)bf3u;
  const bf16x8* f4 = (const bf16x8*)bf4u;
  const bf16x8* fp = (const bf16x8*)bfpu;
  bf16x8 b3H[8], b3L[8];                   // d1 [g*2+s]
  bf16x8 b4H[16], b4L[16];                 // d2 [g*4+s]
  bf16x8 bpH[2], bpL[2];                   // proj [s]
  #pragma unroll
  for (int g = 0; g < 4; ++g){
    #pragma unroll
    for (int s = 0; s < 2; ++s){
      size_t idx = (size_t)(((wid + 4 * g) * 2 + s) * 64 + lane);
      b3H[g * 2 + s] = f3[2 * idx];
      b3L[g * 2 + s] = f3[2 * idx + 1];
    }
    #pragma unroll
    for (int s = 0; s < 4; ++s){
      size_t idx = (size_t)(((wid + 4 * g) * 4 + s) * 64 + lane);
      b4H[g * 4 + s] = f4[2 * idx];
      b4L[g * 4 + s] = f4[2 * idx + 1];
    }
  }
  #pragma unroll
  for (int s = 0; s < 2; ++s){
    size_t idx = (size_t)((wid * 2 + s) * 64 + lane);
    bpH[s] = fp[2 * idx];
    bpL[s] = fp[2 * idx + 1];
  }

  f32x4 init3[4], init4[4];
  #pragma unroll
  for (int g = 0; g < 4; ++g){
    #pragma unroll
    for (int r = 0; r < 4; ++r)
      init3[g][r] = gxin[(size_t)(s0 + 4 * l4 + r) * 256 + jj + 64 * g];
    float b = d2_bih[g * 64 + jj] + d2_bhh[g * 64 + jj];
    init4[g] = (f32x4){b, b, b, b};
  }
  float bp = (jj < 51) ? b_out[jj] : 0.0f;
  const f32x4 biasP = (f32x4){bp, bp, bp, bp};

  for (int i = tid; i < 16 * SA3; i += 256){
    A3H[0][i] = 0; A3H[1][i] = 0; A3L[0][i] = 0; A3L[1][i] = 0;
  }
  for (int i = tid; i < 16 * SA4; i += 256){
    A4H[0][i] = 0; A4H[1][i] = 0; A4L[0][i] = 0; A4L[1][i] = 0;
  }
  __syncthreads();

  float cc3[4] = {0.f,0.f,0.f,0.f}, cc4[4] = {0.f,0.f,0.f,0.f};

#define DEC_STEP(TCUR, BSEL)                                                   \
  {                                                                            \
    const int t = (TCUR);                                                      \
    if (t < T_){  /* d1 step t */                                              \
      bf16x8 a3H[2], a3L[2];                                                   \
      _Pragma("unroll")                                                        \
      for (int s = 0; s < 2; ++s){                                             \
        a3H[s] = *(const bf16x8*)&A3H[BSEL][l15 * SA3 + 32 * s + 8 * l4];      \
        a3L[s] = *(const bf16x8*)&A3L[BSEL][l15 * SA3 + 32 * s + 8 * l4];      \
      }                                                                        \
      f32x4 acc[4];                                                            \
      _Pragma("unroll")                                                        \
      for (int g = 0; g < 4; ++g)                                              \
        acc[g] = dot3<2>(a3H, a3L, &b3H[g * 2], &b3L[g * 2], init3[g]);        \
      float hv[4]; unsigned short hH[4], hL[4];                                \
      pw(acc, cc3, hv, hH, hL);                                                \
      _Pragma("unroll")                                                        \
      for (int r = 0; r < 4; ++r){                                             \
        int rw = 4 * l4 + r;                                                   \
        A3H[BSEL ^ 1][rw * SA3 + jj] = hH[r];                                  \
        A3L[BSEL ^ 1][rw * SA3 + jj] = hL[r];                                  \
        A4H[BSEL ^ 1][rw * SA4 + jj] = hH[r];                                  \
        A4L[BSEL ^ 1][rw * SA4 + jj] = hL[r];                                  \
      }                                                                        \
    }                                                                          \
    if (t >= 1){                                                               \
      bf16x8 a4H[4], a4L[4];                                                   \
      _Pragma("unroll")                                                        \
      for (int s = 0; s < 4; ++s){                                             \
        a4H[s] = *(const bf16x8*)&A4H[BSEL][l15 * SA4 + 32 * s + 8 * l4];      \
        a4L[s] = *(const bf16x8*)&A4L[BSEL][l15 * SA4 + 32 * s + 8 * l4];      \
      }                                                                        \
      if (t <= T_){  /* d2 computes h4_{t-1} */                                \
        f32x4 acc[4];                                                          \
        _Pragma("unroll")                                                      \
        for (int g = 0; g < 4; ++g)                                            \
          acc[g] = dot3<4>(a4H, a4L, &b4H[g * 4], &b4L[g * 4], init4[g]);      \
        float hv[4]; unsigned short hH[4], hL[4];                              \
        pw(acc, cc4, hv, hH, hL);                                              \
        _Pragma("unroll")                                                      \
        for (int r = 0; r < 4; ++r){                                           \
          int rw = 4 * l4 + r;                                                 \
          A4H[BSEL ^ 1][rw * SA4 + 64 + jj] = hH[r];                           \
          A4L[BSEL ^ 1][rw * SA4 + 64 + jj] = hL[r];                           \
        }                                                                      \
      }                                                                        \
      if (t >= 2){  /* proj of h4_{t-2} (A4 h-section = a4[2..3]) */           \
        f32x4 pr = dot3<2>(&a4H[2], &a4L[2], bpH, bpL, biasP);                 \
        if (jj < 51){                                                          \
          _Pragma("unroll")                                                    \
          for (int r = 0; r < 4; ++r)                                          \
            out[((size_t)(s0 + 4 * l4 + r) * T_ + (t - 2)) * 51 + jj] = pr[r]; \
        }                                                                      \
      }                                                                        \
    }                                                                          \
    asm volatile("s_waitcnt lgkmcnt(0)\n\ts_barrier" ::: "memory");            \
  }

  #pragma unroll 1
  for (int tt = 0; tt < 102; tt += 2){
    DEC_STEP(tt,     0)
    DEC_STEP(tt + 1, 1)
  }
#undef DEC_STEP
}

extern "C" void kernel_launch(void* const* d_in, const int* in_sizes, int n_in,
                              void* d_out, int out_size, void* d_ws, size_t ws_size,
                              hipStream_t stream)
{
  (void)in_sizes; (void)n_in; (void)out_size; (void)ws_size;
  const float* x      = (const float*)d_in[0];
  const float* e1_wih = (const float*)d_in[1];
  const float* e1_whh = (const float*)d_in[2];
  const float* e1_bih = (const float*)d_in[3];
  const float* e1_bhh = (const float*)d_in[4];
  const float* e2_wih = (const float*)d_in[5];
  const float* e2_whh = (const float*)d_in[6];
  const float* e2_bih = (const float*)d_in[7];
  const float* e2_bhh = (const float*)d_in[8];
  const float* d1_wih = (const float*)d_in[9];
  const float* d1_whh = (const float*)d_in[10];
  const float* d1_bih = (const float*)d_in[11];
  const float* d1_bhh = (const float*)d_in[12];
  const float* d2_wih = (const float*)d_in[13];
  const float* d2_whh = (const float*)d_in[14];
  const float* d2_bih = (const float*)d_in[15];
  const float* d2_bhh = (const float*)d_in[16];
  const float* w_out  = (const float*)d_in[17];
  const float* b_out  = (const float*)d_in[18];

  char* ws = (char*)d_ws;
  unsigned short* bfrag = (unsigned short*)ws;                   // 393,216 B
  const size_t BF_L2 = 131072, BF_L3 = 180224, BF_L4 = 245760, BF_PR = 376832;
  float* zbuf  = (float*)(ws + 393216);                          // 196,608 B
  float* gxbuf = (float*)(ws + 393216 + 196608);                 // 2,097,152 B

  prep_frags<<<96, 256, 0, stream>>>(e1_wih, e1_whh, e2_wih, e2_whh,
                                     d1_whh, d2_wih, d2_whh, w_out, bfrag);
  // F1: x -> (e1 -> e2, fused) -> z[B,24]
  fused_enc<<<128, 256, 0, stream>>>(
      x, bfrag, bfrag + BF_L2 / 2, e1_bih, e1_bhh, e2_bih, e2_bhh, zbuf);
  // decoder-1 constant input contribution (exact fp32)
  gx_k<<<2048, 256, 0, stream>>>(zbuf, d1_wih, d1_bih, d1_bhh, gxbuf);
  // F2: gx -> (d1 -> d2 -> proj, fused) -> recon[B,T,51] fp32
  fused_dec<<<128, 256, 0, stream>>>(
      gxbuf, bfrag + BF_L3 / 2, bfrag + BF_L4 / 2, bfrag + BF_PR / 2,
      d2_bih, d2_bhh, b_out, (float*)d_out);
}

// Round 6
// 291.985 us; speedup vs baseline: 2.0403x; 1.3863x over previous
//
#include <hip/hip_runtime.h>
#include <stdint.h>

typedef __attribute__((ext_vector_type(8))) __bf16 bf16x8;
typedef __attribute__((ext_vector_type(4))) float f32x4;
typedef __attribute__((ext_vector_type(4))) unsigned int uint4v;

#define DI __device__ __forceinline__
#define MFMA_(a,b,c) __builtin_amdgcn_mfma_f32_16x16x32_bf16(a,b,c,0,0,0)

static constexpr int B_ = 2048;
static constexpr int T_ = 100;

DI float bf2f(unsigned short u){
  unsigned int i = ((unsigned int)u) << 16;
  float f; __builtin_memcpy(&f, &i, 4); return f;
}
DI unsigned short f2bf(float f){
  unsigned int x; __builtin_memcpy(&x, &f, 4);
  unsigned int r = (x + 0x7fffu + ((x >> 16) & 1u)) >> 16;
  return (unsigned short)r;
}
// HW packed rounding: D[15:0]=bf16(a), D[31:16]=bf16(b). RNE, matches f2bf.
DI unsigned int pk2bf(float a, float b){
  unsigned int r;
  asm("v_cvt_pk_bf16_f32 %0, %1, %2" : "=v"(r) : "v"(a), "v"(b));
  return r;
}
DI float rcp_(float x){ return __builtin_amdgcn_rcpf(x); }
DI float sig_(float x){ return rcp_(1.0f + __expf(-x)); }
DI float tanh_(float x){ return 1.0f - 2.0f * rcp_(__expf(2.0f * x) + 1.0f); }

// 2-pass split-weight MFMA dot: A(bf16) x (Bhi + Blo). Two independent chains.
template<int KS>
DI f32x4 dot2(const bf16x8* aH, const bf16x8* bH, const bf16x8* bL, f32x4 ini)
{
  f32x4 p = ini;
  f32x4 q = (f32x4){0.f,0.f,0.f,0.f};
  #pragma unroll
  for (int s = 0; s < KS; ++s){
    p = MFMA_(aH[s], bH[s], p);
    q = MFMA_(aH[s], bL[s], q);
  }
  return p + q;
}

// LSTM pointwise: gates i,f,g,o -> c,h; h rounded to bf16 via cvt_pk.
DI void pw(const f32x4 (&acc)[4], float (&cc)[4], float (&hv)[4],
           unsigned short (&hH)[4])
{
  #pragma unroll
  for (int r = 0; r < 4; ++r){
    float iv = sig_(acc[0][r]);
    float fv = sig_(acc[1][r]);
    float gv = tanh_(acc[2][r]);
    float ov = sig_(acc[3][r]);
    cc[r] = fv * cc[r] + iv * gv;
    hv[r] = ov * tanh_(cc[r]);
  }
  unsigned int u01 = pk2bf(hv[0], hv[1]);
  unsigned int u23 = pk2bf(hv[2], hv[3]);
  hH[0] = (unsigned short)u01; hH[1] = (unsigned short)(u01 >> 16);
  hH[2] = (unsigned short)u23; hH[3] = (unsigned short)(u23 >> 16);
}

// ---------------------------------------------------------------------------
// Pack all weights (fp32 in) into split hi/lo bf16 MFMA B-fragments.
// slot 2*fid+0 = hi, 2*fid+1 = lo. fid layout:
// L1(4096) L2(1536) L3(2048) L4(4096) PROJ(512) = 12288 frags.
// B-frag: lane l holds B[k = 32*s + 8*(l>>4) + e][col = 16*n + (l&15)], e=0..7.
// ---------------------------------------------------------------------------
__global__ __launch_bounds__(256) void prep_frags(
    const float* __restrict__ e1_wih, const float* __restrict__ e1_whh,
    const float* __restrict__ e2_wih, const float* __restrict__ e2_whh,
    const float* __restrict__ d1_whh,
    const float* __restrict__ d2_wih, const float* __restrict__ d2_whh,
    const float* __restrict__ w_out,
    unsigned short* __restrict__ dst)
{
  int ofid = blockIdx.x * 256 + threadIdx.x;
  if (ofid >= 24576) return;
  int piece = ofid & 1, fid = ofid >> 1;
  int layer, local, KS;
  if (fid < 4096)      { layer = 0; local = fid;         KS = 4; }
  else if (fid < 5632) { layer = 1; local = fid - 4096;  KS = 3; }
  else if (fid < 7680) { layer = 2; local = fid - 5632;  KS = 2; }
  else if (fid < 11776){ layer = 3; local = fid - 7680;  KS = 4; }
  else                 { layer = 4; local = fid - 11776; KS = 2; }
  int lane = local & 63;
  int ns = local >> 6;
  int s = ns % KS, n = ns / KS;
  int col = 16 * n + (lane & 15);
  int kb = 32 * s + 8 * (lane >> 4);
  union { unsigned short u[8]; uint4v v; } pk;
  #pragma unroll
  for (int e = 0; e < 8; ++e){
    int k = kb + e;
    float w = 0.0f;
    if (layer == 0){                       // e1: x(51 pad64)|h1(64); K=128, C=256
      if (k < 51) w = e1_wih[col * 51 + k];
      else if (k >= 64) w = e1_whh[col * 64 + (k - 64)];
    } else if (layer == 1){                // e2: h1(64)|h2(24 pad32); K=96, C=128
      int q = col >> 5, jj = col & 31;
      if (jj < 24){
        int r = q * 24 + jj;
        if (k < 64) w = e2_wih[r * 64 + k];
        else if (k < 88) w = e2_whh[r * 24 + (k - 64)];
      }
    } else if (layer == 2){                // d1 recurrent only; K=64, C=256
      w = d1_whh[col * 64 + k];
    } else if (layer == 3){                // d2: h3(64)|h4(64); K=128, C=256
      if (k < 64) w = d2_wih[col * 64 + k];
      else w = d2_whh[col * 64 + (k - 64)];
    } else {                               // proj: K=64, C=64 (51 used)
      if (col < 51) w = w_out[col * 64 + k];
    }
    unsigned short hi = f2bf(w);
    pk.u[e] = piece ? f2bf(w - bf2f(hi)) : hi;
  }
  *(uint4v*)(dst + (size_t)ofid * 8) = pk.v;
}

// Decoder-1 constant input contribution (exact fp32):
// gx[s][col] = b_ih[col] + b_hh[col] + z[s,:]·W_ih[col,:]
__global__ __launch_bounds__(256) void gx_k(
    const float* __restrict__ z, const float* __restrict__ d1_wih,
    const float* __restrict__ bih, const float* __restrict__ bhh,
    float* __restrict__ gx)
{
  int s = blockIdx.x, col = threadIdx.x;
  float acc = bih[col] + bhh[col];
  #pragma unroll
  for (int k = 0; k < 24; ++k)
    acc += z[s * 24 + k] * d1_wih[col * 24 + k];
  gx[s * 256 + col] = acc;
}

// ---------------------------------------------------------------------------
// F1: fused encoder (e1 + e2), 16 batch rows/block, 4 waves.
// All waves compute e1; waves 0,1 run e2 (lag 1); waves 2,3 own x staging.
// State bf16 (A-side), weights split hi/lo (2-pass MFMA).
// ---------------------------------------------------------------------------
__global__ __launch_bounds__(256, 1) void fused_enc(
    const float* xseq,
    const unsigned short* __restrict__ bf1u,
    const unsigned short* __restrict__ bf2u,
    const float* __restrict__ e1_bih, const float* __restrict__ e1_bhh,
    const float* __restrict__ e2_bih, const float* __restrict__ e2_bhh,
    float* __restrict__ zout)
{
  constexpr int SA1 = 136;                 // A1 row stride (ushorts): x(64)|h1(64) pad
  constexpr int SA2 = 104;                 // A2 row stride: h1(64)|h2(32) pad
  __shared__ __align__(16) unsigned short A1H[2][16 * SA1];
  __shared__ __align__(16) unsigned short A2H[2][16 * SA2];

  const int tid = threadIdx.x, lane = tid & 63, wid = tid >> 6;
  const int l15 = lane & 15, l4 = lane >> 4;
  const int jj = 16 * wid + l15;
  const int s0 = blockIdx.x * 16;
  const bool isE2 = (wid < 2);
  const bool isXW = (wid >= 2);
  const int xt = tid - 128;                // 0..127 on staging waves

  const bf16x8* f1 = (const bf16x8*)bf1u;
  const bf16x8* f2 = (const bf16x8*)bf2u;
  bf16x8 b1H[16], b1L[16];                 // e1 frags [g*4+s]
  #pragma unroll
  for (int g = 0; g < 4; ++g)
    #pragma unroll
    for (int s = 0; s < 4; ++s){
      size_t idx = (size_t)(((wid + 4 * g) * 4 + s) * 64 + lane);
      b1H[g * 4 + s] = f1[2 * idx];
      b1L[g * 4 + s] = f1[2 * idx + 1];
    }
  bf16x8 b2H[12], b2L[12];                 // e2 frags [g*3+s] (waves 0,1)
  if (isE2){
    #pragma unroll
    for (int g = 0; g < 4; ++g)
      #pragma unroll
      for (int s = 0; s < 3; ++s){
        size_t idx = (size_t)(((wid + 2 * g) * 3 + s) * 64 + lane);
        b2H[g * 3 + s] = f2[2 * idx];
        b2L[g * 3 + s] = f2[2 * idx + 1];
      }
  }

  f32x4 init1[4], init2[4];
  #pragma unroll
  for (int g = 0; g < 4; ++g){
    float b = e1_bih[g * 64 + jj] + e1_bhh[g * 64 + jj];
    init1[g] = (f32x4){b, b, b, b};
    float b2 = 0.0f;
    if (isE2 && jj < 24) b2 = e2_bih[g * 24 + jj] + e2_bhh[g * 24 + jj];
    init2[g] = (f32x4){b2, b2, b2, b2};
  }

  for (int i = tid; i < 16 * SA1; i += 256){ A1H[0][i] = 0; A1H[1][i] = 0; }
  for (int i = tid; i < 16 * SA2; i += 256){ A2H[0][i] = 0; A2H[1][i] = 0; }
  __syncthreads();
  #pragma unroll
  for (int it = 0; it < 4; ++it){           // stage x_0 (all threads)
    int idx = tid + it * 256, row = idx >> 6, k = idx & 63;
    float v = (k < 51) ? xseq[((size_t)(s0 + row) * T_ + 0) * 51 + k] : 0.0f;
    A1H[0][row * SA1 + k] = f2bf(v);
  }
  __syncthreads();

  float xsA[8], xsB[8];
  if (isXW){
    #pragma unroll
    for (int it = 0; it < 8; ++it){         // prefetch x_1, x_2 (waves 2,3)
      int idx = xt + it * 128, row = idx >> 6, k = idx & 63;
      xsA[it] = (k < 51) ? xseq[((size_t)(s0 + row) * T_ + 1) * 51 + k] : 0.0f;
      xsB[it] = (k < 51) ? xseq[((size_t)(s0 + row) * T_ + 2) * 51 + k] : 0.0f;
    }
  }
  float cc1[4] = {0.f,0.f,0.f,0.f}, cc2[4] = {0.f,0.f,0.f,0.f};

#define ENC_STEP(TCUR, BSEL, XW)                                               \
  {                                                                            \
    const int t = (TCUR);                                                      \
    bf16x8 a1H[4], a2H[3];                                                     \
    if (t < T_){                                                               \
      _Pragma("unroll")                                                        \
      for (int s = 0; s < 4; ++s)                                              \
        a1H[s] = *(const bf16x8*)&A1H[BSEL][l15 * SA1 + 32 * s + 8 * l4];      \
    }                                                                          \
    if (isE2 && t >= 1 && t <= T_){                                            \
      _Pragma("unroll")                                                        \
      for (int s = 0; s < 3; ++s)                                              \
        a2H[s] = *(const bf16x8*)&A2H[BSEL][l15 * SA2 + 32 * s + 8 * l4];      \
    }                                                                          \
    if (t < T_){  /* e1 step t: all waves */                                   \
      f32x4 acc[4];                                                            \
      _Pragma("unroll")                                                        \
      for (int g = 0; g < 4; ++g)                                              \
        acc[g] = dot2<4>(a1H, &b1H[g * 4], &b1L[g * 4], init1[g]);             \
      float hv[4]; unsigned short hH[4];                                       \
      pw(acc, cc1, hv, hH);                                                    \
      _Pragma("unroll")                                                        \
      for (int r = 0; r < 4; ++r){                                             \
        int rw = 4 * l4 + r;                                                   \
        A1H[BSEL ^ 1][rw * SA1 + 64 + jj] = hH[r];                             \
        A2H[BSEL ^ 1][rw * SA2 + jj] = hH[r];                                  \
      }                                                                        \
      if (isXW && t + 1 < T_){  /* x_{t+1} -> LDS, prefetch x_{t+3} */         \
        _Pragma("unroll")                                                      \
        for (int it = 0; it < 8; it += 2){                                     \
          int idx = xt + it * 128;                                             \
          int row0_ = idx >> 6, k0_ = idx & 63;                                \
          int row1_ = (idx + 128) >> 6, k1_ = (idx + 128) & 63;                \
          unsigned int u = pk2bf(XW[it], XW[it + 1]);                          \
          A1H[BSEL ^ 1][row0_ * SA1 + k0_] = (unsigned short)u;                \
          A1H[BSEL ^ 1][row1_ * SA1 + k1_] = (unsigned short)(u >> 16);        \
        }                                                                      \
        if (t + 3 < T_){                                                       \
          _Pragma("unroll")                                                    \
          for (int it = 0; it < 8; ++it){                                      \
            int idx = xt + it * 128, row = idx >> 6, k = idx & 63;             \
            XW[it] = (k < 51) ? xseq[((size_t)(s0 + row) * T_ + (t + 3)) * 51 + k] : 0.0f; \
          }                                                                    \
        }                                                                      \
      }                                                                        \
    }                                                                          \
    if (isE2 && t >= 1 && t <= T_){  /* e2 computes h2_{t-1}: waves 0,1 */     \
      f32x4 acc[4];                                                            \
      _Pragma("unroll")                                                        \
      for (int g = 0; g < 4; ++g)                                              \
        acc[g] = dot2<3>(a2H, &b2H[g * 3], &b2L[g * 3], init2[g]);             \
      float hv[4]; unsigned short hH[4];                                       \
      pw(acc, cc2, hv, hH);                                                    \
      if (jj < 24){                                                            \
        _Pragma("unroll")                                                      \
        for (int r = 0; r < 4; ++r)                                            \
          A2H[BSEL ^ 1][(4 * l4 + r) * SA2 + 64 + jj] = hH[r];                 \
        if (t == T_){                                                          \
          _Pragma("unroll")                                                    \
          for (int r = 0; r < 4; ++r)                                          \
            zout[(size_t)(s0 + 4 * l4 + r) * 24 + jj] = hv[r];                 \
        }                                                                      \
      }                                                                        \
    }                                                                          \
    asm volatile("s_waitcnt lgkmcnt(0)\n\ts_barrier" ::: "memory");            \
  }

  #pragma unroll 1
  for (int tt = 0; tt < 102; tt += 2){
    ENC_STEP(tt,     0, xsA)
    ENC_STEP(tt + 1, 1, xsB)
  }
#undef ENC_STEP
}

// ---------------------------------------------------------------------------
// F2: fused decoder (d1 + d2 + proj), 16 rows/block, 4 waves, all roles on
// every wave. Step t: d1 h3_t (t<=99); d2 h4_{t-1} (1<=t<=100); proj of
// h4_{t-2} (t>=2). h3/h4 pass through LDS; only proj output hits HBM.
// ---------------------------------------------------------------------------
__global__ __launch_bounds__(256, 1) void fused_dec(
    const float* __restrict__ gxin,
    const unsigned short* __restrict__ bf3u,
    const unsigned short* __restrict__ bf4u,
    const unsigned short* __restrict__ bfpu,
    const float* __restrict__ d2_bih, const float* __restrict__ d2_bhh,
    const float* __restrict__ b_out,
    float* out)
{
  constexpr int SA3 = 72;                  // A3: h3(64) pad
  constexpr int SA4 = 136;                 // A4: h3(64)|h4(64) pad
  __shared__ __align__(16) unsigned short A3H[2][16 * SA3];
  __shared__ __align__(16) unsigned short A4H[2][16 * SA4];

  const int tid = threadIdx.x, lane = tid & 63, wid = tid >> 6;
  const int l15 = lane & 15, l4 = lane >> 4;
  const int jj = 16 * wid + l15;
  const int s0 = blockIdx.x * 16;

  const bf16x8* f3 = (const bf16x8*)bf3u;
  const bf16x8* f4 = (const bf16x8*)bf4u;
  const bf16x8* fp = (const bf16x8*)bfpu;
  bf16x8 b3H[8], b3L[8];                   // d1 [g*2+s]
  bf16x8 b4H[16], b4L[16];                 // d2 [g*4+s]
  bf16x8 bpH[2], bpL[2];                   // proj [s]
  #pragma unroll
  for (int g = 0; g < 4; ++g){
    #pragma unroll
    for (int s = 0; s < 2; ++s){
      size_t idx = (size_t)(((wid + 4 * g) * 2 + s) * 64 + lane);
      b3H[g * 2 + s] = f3[2 * idx];
      b3L[g * 2 + s] = f3[2 * idx + 1];
    }
    #pragma unroll
    for (int s = 0; s < 4; ++s){
      size_t idx = (size_t)(((wid + 4 * g) * 4 + s) * 64 + lane);
      b4H[g * 4 + s] = f4[2 * idx];
      b4L[g * 4 + s] = f4[2 * idx + 1];
    }
  }
  #pragma unroll
  for (int s = 0; s < 2; ++s){
    size_t idx = (size_t)((wid * 2 + s) * 64 + lane);
    bpH[s] = fp[2 * idx];
    bpL[s] = fp[2 * idx + 1];
  }

  f32x4 init3[4], init4[4];
  #pragma unroll
  for (int g = 0; g < 4; ++g){
    #pragma unroll
    for (int r = 0; r < 4; ++r)
      init3[g][r] = gxin[(size_t)(s0 + 4 * l4 + r) * 256 + jj + 64 * g];
    float b = d2_bih[g * 64 + jj] + d2_bhh[g * 64 + jj];
    init4[g] = (f32x4){b, b, b, b};
  }
  float bp = (jj < 51) ? b_out[jj] : 0.0f;
  const f32x4 biasP = (f32x4){bp, bp, bp, bp};

  for (int i = tid; i < 16 * SA3; i += 256){ A3H[0][i] = 0; A3H[1][i] = 0; }
  for (int i = tid; i < 16 * SA4; i += 256){ A4H[0][i] = 0; A4H[1][i] = 0; }
  __syncthreads();

  float cc3[4] = {0.f,0.f,0.f,0.f}, cc4[4] = {0.f,0.f,0.f,0.f};

#define DEC_STEP(TCUR, BSEL)                                                   \
  {                                                                            \
    const int t = (TCUR);                                                      \
    bf16x8 a3H[2], a4H[4];                                                     \
    if (t < T_){                                                               \
      _Pragma("unroll")                                                        \
      for (int s = 0; s < 2; ++s)                                              \
        a3H[s] = *(const bf16x8*)&A3H[BSEL][l15 * SA3 + 32 * s + 8 * l4];      \
    }                                                                          \
    if (t >= 1){                                                               \
      _Pragma("unroll")                                                        \
      for (int s = 0; s < 4; ++s)                                              \
        a4H[s] = *(const bf16x8*)&A4H[BSEL][l15 * SA4 + 32 * s + 8 * l4];      \
    }                                                                          \
    if (t < T_){  /* d1 step t */                                              \
      f32x4 acc[4];                                                            \
      _Pragma("unroll")                                                        \
      for (int g = 0; g < 4; ++g)                                              \
        acc[g] = dot2<2>(a3H, &b3H[g * 2], &b3L[g * 2], init3[g]);             \
      float hv[4]; unsigned short hH[4];                                       \
      pw(acc, cc3, hv, hH);                                                    \
      _Pragma("unroll")                                                        \
      for (int r = 0; r < 4; ++r){                                             \
        int rw = 4 * l4 + r;                                                   \
        A3H[BSEL ^ 1][rw * SA3 + jj] = hH[r];                                  \
        A4H[BSEL ^ 1][rw * SA4 + jj] = hH[r];                                  \
      }                                                                        \
    }                                                                          \
    if (t >= 1 && t <= T_){  /* d2 computes h4_{t-1} */                        \
      f32x4 acc[4];                                                            \
      _Pragma("unroll")                                                        \
      for (int g = 0; g < 4; ++g)                                              \
        acc[g] = dot2<4>(a4H, &b4H[g * 4], &b4L[g * 4], init4[g]);             \
      float hv[4]; unsigned short hH[4];                                       \
      pw(acc, cc4, hv, hH);                                                    \
      _Pragma("unroll")                                                        \
      for (int r = 0; r < 4; ++r)                                              \
        A4H[BSEL ^ 1][(4 * l4 + r) * SA4 + 64 + jj] = hH[r];                   \
    }                                                                          \
    if (t >= 2){  /* proj of h4_{t-2} (A4 h-section = a4H[2..3]) */            \
      f32x4 pr = dot2<2>(&a4H[2], bpH, bpL, biasP);                            \
      if (jj < 51){                                                            \
        _Pragma("unroll")                                                      \
        for (int r = 0; r < 4; ++r)                                            \
          out[((size_t)(s0 + 4 * l4 + r) * T_ + (t - 2)) * 51 + jj] = pr[r];   \
      }                                                                        \
    }                                                                          \
    asm volatile("s_waitcnt lgkmcnt(0)\n\ts_barrier" ::: "memory");            \
  }

  #pragma unroll 1
  for (int tt = 0; tt < 102; tt += 2){
    DEC_STEP(tt,     0)
    DEC_STEP(tt + 1, 1)
  }
#undef DEC_STEP
}

extern "C" void kernel_launch(void* const* d_in, const int* in_sizes, int n_in,
                              void* d_out, int out_size, void* d_ws, size_t ws_size,
                              hipStream_t stream)
{
  (void)in_sizes; (void)n_in; (void)out_size; (void)ws_size;
  const float* x      = (const float*)d_in[0];
  const float* e1_wih = (const float*)d_in[1];
  const float* e1_whh = (const float*)d_in[2];
  const float* e1_bih = (const float*)d_in[3];
  const float* e1_bhh = (const float*)d_in[4];
  const float* e2_wih = (const float*)d_in[5];
  const float* e2_whh = (const float*)d_in[6];
  const float* e2_bih = (const float*)d_in[7];
  const float* e2_bhh = (const float*)d_in[8];
  const float* d1_wih = (const float*)d_in[9];
  const float* d1_whh = (const float*)d_in[10];
  const float* d1_bih = (const float*)d_in[11];
  const float* d1_bhh = (const float*)d_in[12];
  const float* d2_wih = (const float*)d_in[13];
  const float* d2_whh = (const float*)d_in[14];
  const float* d2_bih = (const float*)d_in[15];
  const float* d2_bhh = (const float*)d_in[16];
  const float* w_out  = (const float*)d_in[17];
  const float* b_out  = (const float*)d_in[18];

  char* ws = (char*)d_ws;
  unsigned short* bfrag = (unsigned short*)ws;                   // 393,216 B
  const size_t BF_L2 = 131072, BF_L3 = 180224, BF_L4 = 245760, BF_PR = 376832;
  float* zbuf  = (float*)(ws + 393216);                          // 196,608 B
  float* gxbuf = (float*)(ws + 393216 + 196608);                 // 2,097,152 B

  prep_frags<<<96, 256, 0, stream>>>(e1_wih, e1_whh, e2_wih, e2_whh,
                                     d1_whh, d2_wih, d2_whh, w_out, bfrag);
  // F1: x -> (e1 -> e2, fused) -> z[B,24]
  fused_enc<<<128, 256, 0, stream>>>(
      x, bfrag, bfrag + BF_L2 / 2, e1_bih, e1_bhh, e2_bih, e2_bhh, zbuf);
  // decoder-1 constant input contribution (exact fp32)
  gx_k<<<2048, 256, 0, stream>>>(zbuf, d1_wih, d1_bih, d1_bhh, gxbuf);
  // F2: gx -> (d1 -> d2 -> proj, fused) -> recon[B,T,51] fp32
  fused_dec<<<128, 256, 0, stream>>>(
      gxbuf, bfrag + BF_L3 / 2, bfrag + BF_L4 / 2, bfrag + BF_PR / 2,
      d2_bih, d2_bhh, b_out, (float*)d_out);
}